// Round 1
// baseline (310.815 us; speedup 1.0000x reference)
//
#include <hip/hip_runtime.h>
#include <cstdint>
#include <cstddef>

// SelfAttention: B=8, S=2048, D=512, fp32 in/out.
// R6: flash kernel restructured for overlap + LDS-read reduction.
//  - KT=64 key tiles; dedicated K (64KB) and V (64KB) LDS buffers.
//  - Raw s_waitcnt+s_barrier asm (no __syncthreads vmcnt-drain in main loop):
//    V(kt) prefetch flies under phase A+B, K(kt+1) under phase C.
//  - Phase C split by d across waves: each wave does ALL 64 q-rows x 128 d.
//    V-frag reused 4x (row-groups), P-frag 8x (d-cols): 24 LDS reads/wave/kt
//    instead of 128. alpha/l broadcast via small LDS buffers.
// ws: [qh 16M][kh 16M][vh 16M][vt 16M (xh aliases)][Wt 1.5M] = 65.5 MiB.

#define SEQ 2048
#define DIM 512
#define NB 8
#define BSZ (NB * SEQ)
#define KT 64
#define NT (SEQ / KT)

typedef __attribute__((ext_vector_type(8))) _Float16 half8;
typedef __attribute__((ext_vector_type(4))) float f32x4;

__device__ __forceinline__ unsigned short f2h(float f) {
  _Float16 h = (_Float16)f;
  return __builtin_bit_cast(unsigned short, h);
}
__device__ __forceinline__ half8 ld_frag(const unsigned short* p) {
  return *(const half8*)(const void*)p;
}
__device__ __forceinline__ void gl_lds16(const unsigned short* g, unsigned short* l) {
  __builtin_amdgcn_global_load_lds(
      (__attribute__((address_space(1))) void*)g,
      (__attribute__((address_space(3))) void*)l, 16, 0, 0);
}
// Raw barriers: waitcnt + s_barrier fused in ONE asm block so no memory op can
// be scheduled between the wait and the barrier. "memory" clobber = compiler fence.
__device__ __forceinline__ void bar_vm0() {
  asm volatile("s_waitcnt vmcnt(0)\ns_barrier" ::: "memory");
}
__device__ __forceinline__ void bar_lgkm_vm0() {
  asm volatile("s_waitcnt lgkmcnt(0) vmcnt(0)\ns_barrier" ::: "memory");
}

// ---------------------------------------------------------------------------
__global__ __launch_bounds__(256) void cvt_x_kernel(
    const float* __restrict__ X, unsigned short* __restrict__ xh)
{
  size_t i0 = ((size_t)blockIdx.x * 256 + threadIdx.x) * 8;
  float4 a = *(const float4*)&X[i0];
  float4 b = *(const float4*)&X[i0 + 4];
  ushort4 o0; o0.x = f2h(a.x); o0.y = f2h(a.y); o0.z = f2h(a.z); o0.w = f2h(a.w);
  ushort4 o1; o1.x = f2h(b.x); o1.y = f2h(b.y); o1.z = f2h(b.z); o1.w = f2h(b.w);
  *(ushort4*)&xh[i0] = o0;
  *(ushort4*)&xh[i0 + 4] = o1;
}

// ---------------------------------------------------------------------------
__global__ __launch_bounds__(256) void cvt_w_kernel(
    const float* __restrict__ Wq, const float* __restrict__ Wk,
    const float* __restrict__ Wv, unsigned short* __restrict__ Wt)
{
  const int z = blockIdx.z;
  const float* W = (z == 0) ? Wq : (z == 1) ? Wk : Wv;
  unsigned short* out = Wt + (size_t)z * DIM * DIM;
  const int k0 = blockIdx.x * 64, n0 = blockIdx.y * 64;
  const int t = threadIdx.x;
  __shared__ unsigned short tl[64 * 72];
#pragma unroll
  for (int i = 0; i < 4; i++) {
    int f = t + 256 * i;
    int kr = f >> 4, c4 = (f & 15) * 4;
    float4 v = *(const float4*)&W[(size_t)(k0 + kr) * DIM + n0 + c4];
    tl[(c4 + 0) * 72 + kr] = f2h(v.x);
    tl[(c4 + 1) * 72 + kr] = f2h(v.y);
    tl[(c4 + 2) * 72 + kr] = f2h(v.z);
    tl[(c4 + 3) * 72 + kr] = f2h(v.w);
  }
  __syncthreads();
#pragma unroll
  for (int i = 0; i < 2; i++) {
    int f = t + 256 * i;
    int nr = f >> 3, k8 = (f & 7) * 8;
    *(uint4*)&out[(size_t)(n0 + nr) * DIM + k0 + k8] = *(const uint4*)&tl[nr * 72 + k8];
  }
}

// ---------------------------------------------------------------------------
// proj (unchanged): qkv[z] = fp16(xh @ Wt[z]^T + b[z]).
// ---------------------------------------------------------------------------
__global__ __launch_bounds__(256) void proj_kernel(
    const unsigned short* __restrict__ xh, const unsigned short* __restrict__ Wt,
    const float* __restrict__ bq, const float* __restrict__ bk,
    const float* __restrict__ bv, unsigned short* __restrict__ outbase)
{
  const int z = blockIdx.z;
  const unsigned short* Wz = Wt + (size_t)z * DIM * DIM;
  const float* bias = (z == 0) ? bq : (z == 1) ? bk : bv;
  unsigned short* out = outbase + (size_t)z * BSZ * DIM;
  const int m0 = blockIdx.x * 128, n0 = blockIdx.y * 128;
  const int t = threadIdx.x, lane = t & 63, wave = t >> 6;
  const int wrow = (wave >> 1) * 64, wcol = (wave & 1) * 64;
  const int lr = lane & 15, lq = (lane >> 4) * 8;

  __shared__ unsigned short sm[128 * 132];
  unsigned short* As = sm;
  unsigned short* Bs = sm + 128 * 64;

  f32x4 acc[4][4];
  const f32x4 zero = {0.f, 0.f, 0.f, 0.f};
#pragma unroll
  for (int r = 0; r < 4; r++)
#pragma unroll
    for (int c = 0; c < 4; c++) acc[r][c] = zero;

  for (int k0 = 0; k0 < DIM; k0 += 64) {
    __syncthreads();
#pragma unroll
    for (int i = 0; i < 4; i++) {
      int f = t + 256 * i;
      int row = f >> 3, c8 = (f & 7) * 8;
      gl_lds16(&xh[(size_t)(m0 + row) * DIM + k0 + c8], &As[i * 2048 + wave * 512]);
      gl_lds16(&Wz[(size_t)(n0 + row) * DIM + k0 + c8], &Bs[i * 2048 + wave * 512]);
    }
    __syncthreads();
#pragma unroll
    for (int kk = 0; kk < 64; kk += 32) {
      half8 a[4], b[4];
#pragma unroll
      for (int r = 0; r < 4; r++) a[r] = ld_frag(&As[(wrow + 16 * r + lr) * 64 + kk + lq]);
#pragma unroll
      for (int c = 0; c < 4; c++) b[c] = ld_frag(&Bs[(wcol + 16 * c + lr) * 64 + kk + lq]);
#pragma unroll
      for (int r = 0; r < 4; r++)
#pragma unroll
        for (int c = 0; c < 4; c++)
          acc[r][c] = __builtin_amdgcn_mfma_f32_16x16x32_f16(a[r], b[c], acc[r][c], 0, 0, 0);
    }
  }
  __syncthreads();
#pragma unroll
  for (int c = 0; c < 4; c++) {
    float bb = bias[n0 + wcol + 16 * c + lr];
#pragma unroll
    for (int r = 0; r < 4; r++)
#pragma unroll
      for (int e = 0; e < 4; e++)
        sm[(wrow + 16 * r + (lane >> 4) * 4 + e) * 132 + wcol + 16 * c + lr] =
            f2h(acc[r][c][e] + bb);
  }
  __syncthreads();
#pragma unroll
  for (int i = 0; i < 8; i++) {
    int f = t + 256 * i;
    int row = f >> 4, c8 = (f & 15) * 8;
    *(uint4*)&out[(size_t)(m0 + row) * DIM + n0 + c8] = *(const uint4*)&sm[row * 132 + c8];
  }
}

// ---------------------------------------------------------------------------
__global__ __launch_bounds__(256) void vtrans_kernel(
    const unsigned short* __restrict__ vh, unsigned short* __restrict__ vt)
{
  const int b = blockIdx.z;
  const int s0 = blockIdx.x * 64, n0 = blockIdx.y * 64;
  const int t = threadIdx.x;
  __shared__ unsigned short tl[64 * 72];
#pragma unroll
  for (int i = 0; i < 2; i++) {
    int f = t + 256 * i;
    int sr = f >> 3, c8 = (f & 7) * 8;
    uint4 raw = *(const uint4*)&vh[((size_t)b * SEQ + s0 + sr) * DIM + n0 + c8];
    unsigned short u[8];
    *(uint4*)u = raw;
#pragma unroll
    for (int j = 0; j < 8; j++) tl[(c8 + j) * 72 + sr] = u[j];
  }
  __syncthreads();
#pragma unroll
  for (int i = 0; i < 2; i++) {
    int f = t + 256 * i;
    int nr = f >> 3, s8 = (f & 7) * 8;
    *(uint4*)&vt[((size_t)b * DIM + n0 + nr) * SEQ + s0 + s8] = *(const uint4*)&tl[nr * 72 + s8];
  }
}

// ---------------------------------------------------------------------------
// flash R6: O = softmax(Q K^T) V, fused, pipelined.
// Block = 64 Q rows, 4 waves. Per kt (64 keys):
//   top bar (K(kt) landed) -> issue V(kt) -> A: S=QK^T (wave: 16 rows x 64 keys)
//   -> B: online softmax, P/alpha to LDS
//   -> mid bar (lgkm+vm: P visible, V landed) -> issue K(kt+1)
//   -> rescale acc -> C: O += P V (wave: 64 rows x 128-d slice).
// ---------------------------------------------------------------------------
#define PSTR 72   // Pbuf row stride in halves (144 B = 16B-aligned b128 reads)
#define OSTR 516  // Obuf row stride in floats

__global__ __launch_bounds__(256, 1) void flash_kernel(
    const unsigned short* __restrict__ Qb, const unsigned short* __restrict__ Kb,
    const unsigned short* __restrict__ Vtb, float* __restrict__ Ob)
{
  const int zb = blockIdx.x & 7;          // batch -> XCD affinity
  const int q0 = (blockIdx.x >> 3) * 64;  // q-tile base row
  const unsigned short* Q = Qb + (size_t)zb * SEQ * DIM;
  const unsigned short* K = Kb + (size_t)zb * SEQ * DIM;
  const unsigned short* V = Vtb + (size_t)zb * DIM * SEQ;  // [d][s]
  float* Out = Ob + (size_t)zb * SEQ * DIM;

  const int t = threadIdx.x, lane = t & 63, wave = t >> 6;
  const int lr = lane & 15, lq4 = lane >> 4;
  const float L2E = 1.4426950408889634f;

  // LDS carve (halves): KbufK 32768 | KbufV 32768 | Pbuf 64*72 | abuf 64f | lbuf 64f
  __shared__ unsigned short lds[32768 + 32768 + 64 * PSTR + 128 + 128];
  unsigned short* KbufK = lds;                      // [64 keys][512 d]
  unsigned short* KbufV = lds + 32768;              // [512 d][64 keys]
  unsigned short* Pbuf = lds + 65536;               // [64 rows][PSTR]
  float* abuf = (float*)(lds + 65536 + 64 * PSTR);  // alpha[64]
  float* lbuf = abuf + 64;                          // l[64]

  // Per-thread staging source offsets (swizzled): chunk ^= (row&7).
  int koff[16], voff[16];
#pragma unroll
  for (int i = 0; i < 16; i++) {
    int f = t + 256 * i;
    {
      int row = f >> 6, c = f & 63, gc = c ^ (row & 7);  // K: [64 keys][512 d]
      koff[i] = row * DIM + gc * 8;
    }
    {
      int row = f >> 3, c = f & 7, gc = c ^ (row & 7);  // V: [512 d][64 keys]
      voff[i] = row * SEQ + gc * 8;
    }
  }

  // ---- stage Q tile -> KbufK (one 64KB round), read qf ----
#pragma unroll
  for (int i = 0; i < 16; i++)
    gl_lds16(&Q[(size_t)q0 * DIM + koff[i]], &KbufK[i * 2048 + wave * 512]);
  bar_vm0();
  half8 qf[16];
  {
    const int qrow = 16 * wave + lr;
#pragma unroll
    for (int j = 0; j < 16; j++)
      qf[j] = ld_frag(&KbufK[qrow * 512 + (((4 * j + lq4) ^ (qrow & 7)) << 3)]);
  }
  __syncthreads();  // all waves done reading Q before K(0) overwrites

  // issue K(0)
#pragma unroll
  for (int i = 0; i < 16; i++)
    gl_lds16(&K[koff[i]], &KbufK[i * 2048 + wave * 512]);

  // ---- running state ----
  f32x4 acc[32];  // [rg 0..3][dc 0..7]: rows rg*16+lq4*4+e, d wave*128+dc*16+lr
  const f32x4 zero = {0.f, 0.f, 0.f, 0.f};
#pragma unroll
  for (int ob = 0; ob < 32; ob++) acc[ob] = zero;
  float m_run[4], l_run[4];
#pragma unroll
  for (int e = 0; e < 4; e++) { m_run[e] = -__builtin_inff(); l_run[e] = 0.f; }

  for (int kt = 0; kt < NT; kt++) {
    bar_vm0();  // K(kt) staged for all waves

    // issue V(kt) -> flies under phase A+B
    {
      const unsigned short* Vt = V + kt * KT;
#pragma unroll
      for (int i = 0; i < 16; i++)
        gl_lds16(&Vt[voff[i]], &KbufV[i * 2048 + wave * 512]);
    }

    // ===== phase A: S = Q K^T (per wave: 16 rows x 64 keys) =====
    f32x4 sacc[4];
#pragma unroll
    for (int c = 0; c < 4; c++) sacc[c] = zero;
#pragma unroll
    for (int j = 0; j < 16; j++) {
#pragma unroll
      for (int c = 0; c < 4; c++) {
        int key = 16 * c + lr;
        half8 bf = ld_frag(&KbufK[key * 512 + (((4 * j + lq4) ^ (key & 7)) << 3)]);
        sacc[c] = __builtin_amdgcn_mfma_f32_16x16x32_f16(qf[j], bf, sacc[c], 0, 0, 0);
      }
    }

    // ===== phase B: online softmax (rows wave*16 + lq4*4 + e) =====
#pragma unroll
    for (int e = 0; e < 4; e++) {
      float mx = fmaxf(fmaxf(sacc[0][e], sacc[1][e]), fmaxf(sacc[2][e], sacc[3][e]));
      mx = fmaxf(mx, __shfl_xor(mx, 1, 64));
      mx = fmaxf(mx, __shfl_xor(mx, 2, 64));
      mx = fmaxf(mx, __shfl_xor(mx, 4, 64));
      mx = fmaxf(mx, __shfl_xor(mx, 8, 64));
      float mnew = fmaxf(m_run[e], mx);
      float alpha = exp2f((m_run[e] - mnew) * L2E);
      m_run[e] = mnew;
      float sum = 0.f;
#pragma unroll
      for (int c = 0; c < 4; c++) {
        float p = exp2f((sacc[c][e] - mnew) * L2E);
        sum += p;
        Pbuf[(wave * 16 + lq4 * 4 + e) * PSTR + 16 * c + lr] = f2h(p);
      }
      sum += __shfl_xor(sum, 1, 64);
      sum += __shfl_xor(sum, 2, 64);
      sum += __shfl_xor(sum, 4, 64);
      sum += __shfl_xor(sum, 8, 64);
      l_run[e] = alpha * l_run[e] + sum;
      if (lr == 0) abuf[wave * 16 + lq4 * 4 + e] = alpha;
    }

    // mid barrier: Pbuf/abuf visible to all waves; V(kt) staged.
    bar_lgkm_vm0();

    // issue K(kt+1) -> flies under phase C
    if (kt + 1 < NT) {
      const unsigned short* Kt = K + (size_t)(kt + 1) * KT * DIM;
#pragma unroll
      for (int i = 0; i < 16; i++)
        gl_lds16(&Kt[koff[i]], &KbufK[i * 2048 + wave * 512]);
    }

    // rescale acc by alpha (cross-wave broadcast from abuf)
#pragma unroll
    for (int rg = 0; rg < 4; rg++)
#pragma unroll
      for (int e = 0; e < 4; e++) {
        float a = abuf[rg * 16 + lq4 * 4 + e];
#pragma unroll
        for (int dc = 0; dc < 8; dc++) acc[rg * 8 + dc][e] *= a;
      }

    // ===== phase C: O += P V (per wave: ALL 64 rows x 128-d slice) =====
    half8 pf[4][2];
#pragma unroll
    for (int rg = 0; rg < 4; rg++)
#pragma unroll
      for (int ks = 0; ks < 2; ks++)
        pf[rg][ks] = ld_frag(&Pbuf[(rg * 16 + lr) * PSTR + ks * 32 + lq4 * 8]);
#pragma unroll
    for (int dc = 0; dc < 8; dc++) {
      int drow = wave * 128 + 16 * dc + lr;
      half8 vf0 = ld_frag(&KbufV[drow * 64 + ((lq4 ^ (drow & 7)) << 3)]);
      half8 vf1 = ld_frag(&KbufV[drow * 64 + (((4 + lq4) ^ (drow & 7)) << 3)]);
#pragma unroll
      for (int rg = 0; rg < 4; rg++) {
        acc[rg * 8 + dc] =
            __builtin_amdgcn_mfma_f32_16x16x32_f16(pf[rg][0], vf0, acc[rg * 8 + dc], 0, 0, 0);
        acc[rg * 8 + dc] =
            __builtin_amdgcn_mfma_f32_16x16x32_f16(pf[rg][1], vf1, acc[rg * 8 + dc], 0, 0, 0);
      }
    }
  }

  // ---- finalize: O /= l, repack via LDS in 32-row halves, coalesced stores ----
  if (lr == 0) {
#pragma unroll
    for (int e = 0; e < 4; e++) lbuf[wave * 16 + lq4 * 4 + e] = l_run[e];
  }
  __syncthreads();
  float linv[4][4];
#pragma unroll
  for (int rg = 0; rg < 4; rg++)
#pragma unroll
    for (int e = 0; e < 4; e++) linv[rg][e] = 1.0f / lbuf[rg * 16 + lq4 * 4 + e];

  float* Obuf = (float*)lds;  // 32 x OSTR floats = 66 KB (over KbufK/KbufV)
#pragma unroll
  for (int h = 0; h < 2; h++) {
    __syncthreads();
#pragma unroll
    for (int r2 = 0; r2 < 2; r2++) {
      int rg = h * 2 + r2;
#pragma unroll
      for (int e = 0; e < 4; e++) {
        int rowh = r2 * 16 + lq4 * 4 + e;
#pragma unroll
        for (int dc = 0; dc < 8; dc++)
          Obuf[rowh * OSTR + wave * 128 + dc * 16 + lr] = acc[rg * 8 + dc][e] * linv[rg][e];
      }
    }
    __syncthreads();
#pragma unroll
    for (int i = 0; i < 16; i++) {
      int f = t + 256 * i;
      int rowh = f >> 7, c4 = (f & 127) * 4;
      *(float4*)&Out[(size_t)(q0 + h * 32 + rowh) * DIM + c4] =
          *(const float4*)&Obuf[rowh * OSTR + c4];
    }
  }
}

// ---------------------------------------------------------------------------
extern "C" void kernel_launch(void* const* d_in, const int* in_sizes, int n_in,
                              void* d_out, int out_size, void* d_ws, size_t ws_size,
                              hipStream_t stream)
{
  const float* X  = (const float*)d_in[0];
  const float* Wq = (const float*)d_in[1];
  const float* bq = (const float*)d_in[2];
  const float* Wk = (const float*)d_in[3];
  const float* bk = (const float*)d_in[4];
  const float* Wv = (const float*)d_in[5];
  const float* bv = (const float*)d_in[6];
  float* Out = (float*)d_out;

  char* ws = (char*)d_ws;
  const size_t MB = 1u << 20;
  unsigned short* qh = (unsigned short*)(ws);            // 16 MiB
  unsigned short* kh = (unsigned short*)(ws + 16 * MB);  // 16 MiB (proj z=1)
  unsigned short* vh = (unsigned short*)(ws + 32 * MB);  // 16 MiB (proj z=2)
  unsigned short* vt = (unsigned short*)(ws + 48 * MB);  // 16 MiB
  unsigned short* xh = (unsigned short*)(ws + 48 * MB);  // alias vt: dead pre-vtrans
  unsigned short* Wt = (unsigned short*)(ws + 64 * MB);  // 1.5 MiB

  cvt_x_kernel<<<dim3(BSZ * DIM / 2048), 256, 0, stream>>>(X, xh);
  cvt_w_kernel<<<dim3(8, 8, 3), 256, 0, stream>>>(Wq, Wk, Wv, Wt);
  proj_kernel<<<dim3(BSZ / 128, DIM / 128, 3), 256, 0, stream>>>(
      xh, Wt, bq, bk, bv, qh);
  vtrans_kernel<<<dim3(SEQ / 64, DIM / 64, NB), 256, 0, stream>>>(vh, vt);
  flash_kernel<<<dim3(NB * SEQ / 64), 256, 0, stream>>>(qh, kh, vt, Out);
}